// Round 8
// baseline (1007.268 us; speedup 1.0000x reference)
//
#include <hip/hip_runtime.h>
#include <cstdint>
#include <cstddef>

// ---------------------------------------------------------------------------
// CapsNet forward. Round 8:
//  - NO cooperative launch (round-7 k_route never executed; discrete kernels).
//  - conv2 -> k_conv2d: direct global->VGPR MFMA fragments (layouts make every
//    A/B frag a contiguous 16B chunk; 16 cache lines/wave-load = optimal).
//    No LDS, no barriers in the K-loop -> escapes the barrier-drain plateau.
//  - conv1m (MFMA, validated round 6), round-5 routing kernels.
//  - bij memset folded into g2uv iter-0 assignment; outw dropped.
// Workspace (bytes):
//   h    [0, 52428800)           bf16 [b][pix400][ic256]
//   wt   [52428800, 63045632)    bf16 [k81][oc256][ic256]
//   pp   [63045632, 81920000)    f32  2 z-halves of [b][oc][36]
//   U    [81920000, 91357184)    f32  [b][ik]
//   dwT2 [91357184, 97255424)    f32  [co160][ik9216]
//   part [97255424, 102498304)   f32  [kc32][b256][co160]
//   csm  [102498304,102544384)   f32  [i][c]
//   bij  [102544384,102590464)   f32  [i][c]
//   outT [102590464,102754304)   f32  [co160][b256]
//   UT   [102754304,112191488)   f32  [ik9216][b256]
//   wb1  [112191488,112240640)   bf16 conv1 frag-linear weights
// ---------------------------------------------------------------------------

typedef __attribute__((ext_vector_type(8))) short short8;
typedef __attribute__((ext_vector_type(4))) float f32x4;

#define PHALF 2359296

__device__ __forceinline__ unsigned short f2bf_rn(float x) {
    unsigned u = __float_as_uint(x);
    unsigned r = (u + 0x7fffu + ((u >> 16) & 1u)) >> 16;
    return (unsigned short)r;
}

// prim_w (256 oc, 256 ic, 81) fp32 -> wt[k][oc][ic] bf16
__global__ void k_makew(const float* __restrict__ w2,
                        unsigned short* __restrict__ wt) {
    __shared__ float lw[20736];   // [8 oc][32 ic][81 k]
    int ocg = blockIdx.x, icg = blockIdx.y, t = threadIdx.x;
    for (int idx = t; idx < 20736; idx += 256) {
        int row = idx / 81, k = idx % 81;
        int oc_l = row >> 5, ic_l = row & 31;
        lw[idx] = w2[((size_t)(ocg * 8 + oc_l) * 256 + icg * 32 + ic_l) * 81 + k];
    }
    __syncthreads();
    for (int idx = t; idx < 2592; idx += 256) {   // 81 k * 8 oc * 4 slots
        int k = idx >> 5;
        int r = idx & 31;
        int oc_l = r >> 2, sl = r & 3;
        unsigned short hi8[8];
        #pragma unroll
        for (int j = 0; j < 8; j++)
            hi8[j] = f2bf_rn(lw[(oc_l * 32 + sl * 8 + j) * 81 + k]);
        size_t o = ((size_t)(k * 256 + ocg * 8 + oc_l)) * 256 + icg * 32 + sl * 8;
        *(uint4*)&wt[o] = *(uint4*)hi8;
    }
}

// merged prep: blk0 = conv1 weight frags, blk1.. = dwT2[co160][ik9216]
__global__ void k_prep2(const float* __restrict__ cw, const float* __restrict__ dw,
                        unsigned short* __restrict__ wb1, float* __restrict__ dwT2) {
    int blk = blockIdx.x, t = threadIdx.x;
    if (blk == 0) {
        for (int idx = t; idx < 24576; idx += 256) {
            int j = idx & 7, lane = (idx >> 3) & 63;
            int q = (idx >> 9) % 3, nt = idx / 1536;
            int oc = nt * 16 + (lane & 15);
            int kg = q * 32 + (lane >> 4) * 8 + j;
            float v = (kg < 81) ? cw[oc * 81 + kg] : 0.f;
            wb1[idx] = f2bf_rn(v);
        }
    } else {
        int co = blk - 1;                     // 0..159
        int c = co >> 4, o = co & 15;
        const float* base = dw + c * 128 + o * 8;
        float* out = dwT2 + (size_t)co * 9216;
        for (int idx = t; idx < 9216; idx += 256) {
            int i = idx >> 3, k = idx & 7;
            out[idx] = base[(size_t)i * 1280 + k];
        }
    }
}

// MFMA conv1: grid (256 b, 2 ng), block 256 (4 waves). Validated round 6.
__global__ __launch_bounds__(256) void k_conv1m(
    const float* __restrict__ x, const unsigned short* __restrict__ wb1,
    const float* __restrict__ cb, unsigned short* __restrict__ h)
{
    __shared__ unsigned short xb[900];   // [30 rows][30 cols], zero-padded
    int b = blockIdx.x, ng = blockIdx.y, t = threadIdx.x;
    int w = t >> 6, l = t & 63;
    for (int idx = t; idx < 900; idx += 256) {
        int row = idx / 30, col = idx % 30;
        float v = (row < 28 && col < 28) ? x[(size_t)b * 784 + row * 28 + col] : 0.f;
        xb[idx] = f2bf_rn(v);
    }
    __syncthreads();
    int lane16 = l & 15, l4 = l >> 4;
    int ntile = (w == 0) ? 7 : 6;
    short8 afr[7][3];
    for (int i = 0; i < 7; i++) {
        if (i < ntile) {
            int mt = w + 4 * i;
            int pix = mt * 16 + lane16;
            int py = pix / 20, px = pix % 20;
            #pragma unroll
            for (int qq = 0; qq < 3; qq++) {
                int kbase = qq * 32 + l4 * 8;
                unsigned short tmp[8];
                int ky = kbase / 9, kx = kbase - 9 * (kbase / 9);
                #pragma unroll
                for (int j = 0; j < 8; j++) {
                    tmp[j] = xb[(py + ky) * 30 + px + kx];
                    kx++; if (kx == 9) { kx = 0; ky++; }
                }
                afr[i][qq] = *(short8*)tmp;
            }
        }
    }
    for (int nt0 = 0; nt0 < 8; nt0++) {
        int nt = ng * 8 + nt0;
        short8 bfr[3];
        #pragma unroll
        for (int qq = 0; qq < 3; qq++)
            bfr[qq] = *(const short8*)&wb1[(nt * 3 + qq) * 512 + l * 8];
        float bias = cb[nt * 16 + lane16];
        f32x4 acc[7] = {};
        for (int i = 0; i < 7; i++) {
            if (i < ntile) {
                #pragma unroll
                for (int qq = 0; qq < 3; qq++)
                    acc[i] = __builtin_amdgcn_mfma_f32_16x16x32_bf16(afr[i][qq], bfr[qq], acc[i], 0, 0, 0);
            }
        }
        for (int i = 0; i < 7; i++) {
            if (i < ntile) {
                int mt = w + 4 * i;
                int pixb = mt * 16 + l4 * 4;
                size_t base = ((size_t)b * 400 + pixb) * 256 + nt * 16 + lane16;
                #pragma unroll
                for (int r = 0; r < 4; r++) {
                    float v = fmaxf(acc[i][r] + bias, 0.f);
                    h[base + (size_t)r * 256] = f2bf_rn(v);
                }
            }
        }
    }
}

// Direct-load MFMA conv2: NO LDS, NO barriers. grid (72 mb, 4 nb, 2 z),
// block 256 (4 waves, 2x2). Every A/B fragment is a contiguous 16B global
// chunk; lanes 0/16/32/48 cover one 64B line -> 16 lines per wave-load.
__global__ __launch_bounds__(256) void k_conv2d(
    const unsigned short* __restrict__ h,
    const unsigned short* __restrict__ wt,
    float* __restrict__ pp)
{
    const int t = threadIdx.x;
    const int w = t >> 6, l = t & 63;
    const int mb = blockIdx.x, nb = blockIdx.y, z = blockIdx.z;
    const int wm = w & 1, wn = w >> 1;
    const int lane16 = l & 15, q = l >> 4;

    const unsigned short* abase[4];
    #pragma unroll
    for (int mt = 0; mt < 4; mt++) {
        int P = mb * 128 + wm * 64 + mt * 16 + lane16;
        int b = P / 36, o = P % 36;
        int oy = o / 6, ox = o % 6;
        abase[mt] = h + ((size_t)(b * 400 + oy * 40 + ox * 2) * 256 + z * 128 + q * 8);
    }
    const unsigned short* bbase[2];
    #pragma unroll
    for (int nt = 0; nt < 2; nt++) {
        int oc = nb * 64 + wn * 32 + nt * 16 + lane16;
        bbase[nt] = wt + ((size_t)oc * 256 + z * 128 + q * 8);
    }

    f32x4 acc[4][2] = {};

    for (int ky = 0; ky < 9; ky++) {
        for (int kx = 0; kx < 9; kx++) {
            const unsigned aofs = (unsigned)((ky * 20 + kx) * 256);
            const size_t bofs = (size_t)(ky * 9 + kx) * 65536;
            #pragma unroll
            for (int hh = 0; hh < 2; hh++) {
                #pragma unroll
                for (int ic2 = 0; ic2 < 2; ic2++) {
                    const unsigned sub = hh * 64 + ic2 * 32;
                    short8 a[4], b[2];
                    #pragma unroll
                    for (int mt = 0; mt < 4; mt++)
                        a[mt] = *(const short8*)(abase[mt] + aofs + sub);
                    #pragma unroll
                    for (int nt = 0; nt < 2; nt++)
                        b[nt] = *(const short8*)(bbase[nt] + bofs + sub);
                    #pragma unroll
                    for (int mt = 0; mt < 4; mt++)
                        #pragma unroll
                        for (int nt = 0; nt < 2; nt++)
                            acc[mt][nt] = __builtin_amdgcn_mfma_f32_16x16x32_bf16(a[mt], b[nt], acc[mt][nt], 0, 0, 0);
                }
            }
        }
    }

    // epilogue: D row = q*4+reg (pixel), col = lane16 (oc)
    float* pout = pp + (size_t)z * PHALF;
    #pragma unroll
    for (int mt = 0; mt < 4; mt++) {
        int pixG = mb * 128 + wm * 64 + mt * 16 + q * 4;
        int b = pixG / 36, p36 = pixG % 36;
        #pragma unroll
        for (int nt = 0; nt < 2; nt++) {
            int oc = nb * 64 + wn * 32 + nt * 16 + lane16;
            f32x4 v = acc[mt][nt];
            *(f32x4*)&pout[((size_t)(b * 256 + oc)) * 36 + p36] = v;
        }
    }
}

__global__ void k_squash1(const float* __restrict__ pp, const float* __restrict__ prim_b,
                          float* __restrict__ U) {
    __shared__ float red[4];
    int b = blockIdx.x >> 3, cap = blockIdx.x & 7;
    int t = threadIdx.x;
    const float* pa = pp + ((size_t)b * 256 + cap * 32) * 36;
    const float* pc = pa + PHALF;
    float v[5];
    float ss = 0.f;
    #pragma unroll
    for (int j = 0; j < 5; j++) {
        int idx = t + j * 256;
        if (idx < 1152) {
            int ch_l = idx / 36;
            float val = pa[idx] + pc[idx] + prim_b[cap * 32 + ch_l];
            v[j] = val; ss += val * val;
        } else v[j] = 0.f;
    }
    for (int off = 32; off; off >>= 1) ss += __shfl_down(ss, off);
    if ((t & 63) == 0) red[t >> 6] = ss;
    __syncthreads();
    float n2 = red[0] + red[1] + red[2] + red[3];
    float f = (n2 / (1.0f + n2)) / (sqrtf(n2) + 1e-10f);
    #pragma unroll
    for (int j = 0; j < 5; j++) {
        int idx = t + j * 256;
        if (idx < 1152) U[(size_t)b * 9216 + idx * 8 + cap] = v[j] * f;
    }
}

// U[b][ik] -> UT[ik][b], 64x64 tiles (coalesced both sides)
__global__ void k_ut(const float* __restrict__ U, float* __restrict__ UT) {
    __shared__ float tl[64][65];
    int ikb = blockIdx.x, bb = blockIdx.y, t = threadIdx.x;
    for (int idx = t; idx < 1024; idx += 256) {
        int row = idx >> 4, c4 = idx & 15;
        float4 v = *(const float4*)&U[(size_t)(bb * 64 + row) * 9216 + ikb * 64 + c4 * 4];
        tl[c4 * 4 + 0][row] = v.x;
        tl[c4 * 4 + 1][row] = v.y;
        tl[c4 * 4 + 2][row] = v.z;
        tl[c4 * 4 + 3][row] = v.w;
    }
    __syncthreads();
    for (int idx = t; idx < 1024; idx += 256) {
        int row = idx >> 4, c4 = idx & 15;
        float4 v = make_float4(tl[row][c4 * 4 + 0], tl[row][c4 * 4 + 1],
                               tl[row][c4 * 4 + 2], tl[row][c4 * 4 + 3]);
        *(float4*)&UT[(size_t)(ikb * 64 + row) * 256 + bb * 64 + c4 * 4] = v;
    }
}

__global__ void k_softmax(const float* __restrict__ bij, float* __restrict__ csm) {
    __shared__ float red[4];
    int c = blockIdx.x, t = threadIdx.x;
    float vals[5];
    float mx = -1e30f;
    #pragma unroll
    for (int j = 0; j < 5; j++) {
        int i = t + j * 256;
        vals[j] = (i < 1152) ? bij[i * 10 + c] : -1e30f;
        mx = fmaxf(mx, vals[j]);
    }
    for (int off = 32; off; off >>= 1) mx = fmaxf(mx, __shfl_down(mx, off));
    if ((t & 63) == 0) red[t >> 6] = mx;
    __syncthreads();
    mx = fmaxf(fmaxf(red[0], red[1]), fmaxf(red[2], red[3]));
    __syncthreads();
    float s = 0.f;
    #pragma unroll
    for (int j = 0; j < 5; j++) {
        int i = t + j * 256;
        vals[j] = (i < 1152) ? expf(vals[j] - mx) : 0.f;
        s += vals[j];
    }
    for (int off = 32; off; off >>= 1) s += __shfl_down(s, off);
    if ((t & 63) == 0) red[t >> 6] = s;
    __syncthreads();
    s = red[0] + red[1] + red[2] + red[3];
    float inv = 1.0f / s;
    #pragma unroll
    for (int j = 0; j < 5; j++) {
        int i = t + j * 256;
        if (i < 1152) csm[i * 10 + c] = vals[j] * inv;
    }
}

// s_j partial GEMM. A-panel register cache + b128 swizzled WsT reads.
__global__ __launch_bounds__(256) void k_gemm1(const float* __restrict__ U,
                                               const float* __restrict__ dwT2,
                                               const float* __restrict__ csm,
                                               float* __restrict__ part,
                                               int uniform) {
    __shared__ float Us[32 * 36];
    __shared__ float WsT[5120];
    __shared__ float cl[360];
    int mb = blockIdx.x, kc = blockIdx.y, t = threadIdx.x;
    int tc = t & 15, tb = t >> 4;
    if (!uniform)
        for (int idx = t; idx < 360; idx += 256) cl[idx] = csm[kc * 360 + idx];
    const float uscale = 1.0f / 1152.0f;
    float acc[2][10] = {};
    for (int ks = 0; ks < 9; ks++) {
        __syncthreads();
        {
            int bb = t >> 3, k4 = t & 7;
            *(float4*)&Us[bb * 36 + k4 * 4] =
                *(const float4*)&U[(size_t)(mb * 32 + bb) * 9216 + kc * 288 + ks * 32 + k4 * 4];
        }
        #pragma unroll
        for (int pass = 0; pass < 5; pass++) {
            int s = t + pass * 256;
            int co = s >> 3, p = s & 7;
            int kq = p ^ (co & 7);
            int ikl = ks * 32 + kq * 4;
            float4 v = *(const float4*)&dwT2[(size_t)co * 9216 + kc * 288 + ikl];
            float sc = uniform ? uscale : cl[(ikl >> 3) * 10 + (co >> 4)];
            v.x *= sc; v.y *= sc; v.z *= sc; v.w *= sc;
            *(float4*)&WsT[s * 4] = v;
        }
        __syncthreads();
        float a0[32], a1[32];
        #pragma unroll
        for (int kq = 0; kq < 8; kq++) {
            float4 v0 = *(const float4*)&Us[(tb * 2) * 36 + kq * 4];
            float4 v1 = *(const float4*)&Us[(tb * 2 + 1) * 36 + kq * 4];
            a0[kq * 4 + 0] = v0.x; a0[kq * 4 + 1] = v0.y; a0[kq * 4 + 2] = v0.z; a0[kq * 4 + 3] = v0.w;
            a1[kq * 4 + 0] = v1.x; a1[kq * 4 + 1] = v1.y; a1[kq * 4 + 2] = v1.z; a1[kq * 4 + 3] = v1.w;
        }
        #pragma unroll
        for (int j = 0; j < 10; j++) {
            int co = tc + 16 * j;
            int cx = co & 7, cbase = co * 32;
            #pragma unroll
            for (int kq = 0; kq < 8; kq++) {
                float4 wv = *(const float4*)&WsT[cbase + ((kq ^ cx) << 2)];
                acc[0][j] += a0[kq * 4 + 0] * wv.x; acc[0][j] += a0[kq * 4 + 1] * wv.y;
                acc[0][j] += a0[kq * 4 + 2] * wv.z; acc[0][j] += a0[kq * 4 + 3] * wv.w;
                acc[1][j] += a1[kq * 4 + 0] * wv.x; acc[1][j] += a1[kq * 4 + 1] * wv.y;
                acc[1][j] += a1[kq * 4 + 2] * wv.z; acc[1][j] += a1[kq * 4 + 3] * wv.w;
            }
        }
    }
    #pragma unroll
    for (int r = 0; r < 2; r++)
        #pragma unroll
        for (int j = 0; j < 10; j++)
            part[(size_t)kc * 40960 + (mb * 32 + tb * 2 + r) * 160 + tc + 16 * j] = acc[r][j];
}

// reduce 32 partials + class-axis squash; iters 0/1 -> outT, iter 2 -> dout
__global__ void k_redsq(const float* __restrict__ part, float* __restrict__ outT,
                        float* __restrict__ dout, int last) {
    __shared__ float sl[160];
    __shared__ float n2s[16];
    int b = blockIdx.x, t = threadIdx.x;
    float s = 0.f;
    if (t < 160) {
        for (int kc = 0; kc < 32; kc++) s += part[(size_t)kc * 40960 + b * 160 + t];
        sl[t] = s;
    }
    __syncthreads();
    if (t < 16) {
        float n2 = 0.f;
        #pragma unroll
        for (int c = 0; c < 10; c++) { float v = sl[c * 16 + t]; n2 += v * v; }
        n2s[t] = n2;
    }
    __syncthreads();
    if (t < 160) {
        float n2 = n2s[t & 15];
        float f = (n2 / (1.0f + n2)) / (sqrtf(n2) + 1e-10f);
        float r = s * f;
        if (last) dout[(size_t)b * 160 + t] = r;
        else      outT[(size_t)t * 256 + b] = r;
    }
}

// Fused agreement via UT/outT. grid 288 (4 i's each), block 256.
__global__ __launch_bounds__(256) void k_g2uv(const float* __restrict__ UT,
                                              const float* __restrict__ outTg,
                                              const float* __restrict__ dw,
                                              float* __restrict__ bij, int init) {
    __shared__ float UsT[1024];
    __shared__ float OsT[5120];
    __shared__ float dwl[5120];
    __shared__ float sb[320];
    int blk = blockIdx.x, t = threadIdx.x;
    int tc = t & 15, tm = t >> 4;
    for (int idx = t; idx < 5120; idx += 256)
        dwl[idx] = dw[(size_t)blk * 5120 + idx];
    float acc[2][10] = {};
    for (int bs = 0; bs < 256; bs += 32) {
        __syncthreads();
        {
            int m = t >> 3, p = t & 7;
            int kq = p ^ (m & 7);
            *(float4*)&UsT[t * 4] =
                *(const float4*)&UT[(size_t)(blk * 32 + m) * 256 + bs + kq * 4];
        }
        #pragma unroll
        for (int pass = 0; pass < 5; pass++) {
            int s = t + pass * 256;
            int co = s >> 3, p = s & 7;
            int kq = p ^ (co & 7);
            *(float4*)&OsT[s * 4] =
                *(const float4*)&outTg[(size_t)co * 256 + bs + kq * 4];
        }
        __syncthreads();
        float a0[32], a1[32];
        int m0 = tm * 2, m1 = tm * 2 + 1;
        #pragma unroll
        for (int kq = 0; kq < 8; kq++) {
            float4 v0 = *(const float4*)&UsT[m0 * 32 + ((kq ^ (m0 & 7)) << 2)];
            float4 v1 = *(const float4*)&UsT[m1 * 32 + ((kq ^ (m1 & 7)) << 2)];
            a0[kq * 4 + 0] = v0.x; a0[kq * 4 + 1] = v0.y; a0[kq * 4 + 2] = v0.z; a0[kq * 4 + 3] = v0.w;
            a1[kq * 4 + 0] = v1.x; a1[kq * 4 + 1] = v1.y; a1[kq * 4 + 2] = v1.z; a1[kq * 4 + 3] = v1.w;
        }
        #pragma unroll
        for (int j = 0; j < 10; j++) {
            int co = tc + 16 * j;
            int cx = co & 7, cbase = co * 32;
            #pragma unroll
            for (int kq = 0; kq < 8; kq++) {
                float4 wv = *(const float4*)&OsT[cbase + ((kq ^ cx) << 2)];
                acc[0][j] += a0[kq * 4 + 0] * wv.x; acc[0][j] += a0[kq * 4 + 1] * wv.y;
                acc[0][j] += a0[kq * 4 + 2] * wv.z; acc[0][j] += a0[kq * 4 + 3] * wv.w;
                acc[1][j] += a1[kq * 4 + 0] * wv.x; acc[1][j] += a1[kq * 4 + 1] * wv.y;
                acc[1][j] += a1[kq * 4 + 2] * wv.z; acc[1][j] += a1[kq * 4 + 3] * wv.w;
            }
        }
    }
    #pragma unroll
    for (int r = 0; r < 2; r++) {
        int ik_l = tm * 2 + r;
        int i_l = ik_l >> 3, k = ik_l & 7;
        #pragma unroll
        for (int j = 0; j < 10; j++) {
            float v = acc[r][j] * dwl[i_l * 1280 + (j * 16 + tc) * 8 + k];
            v += __shfl_down(v, 8, 16);
            v += __shfl_down(v, 4, 16);
            v += __shfl_down(v, 2, 16);
            v += __shfl_down(v, 1, 16);
            if (tc == 0) sb[ik_l * 10 + j] = v;
        }
    }
    __syncthreads();
    if (t < 40) {
        int i_l = t / 10, c = t % 10;
        float s = 0.f;
        #pragma unroll
        for (int kk = 0; kk < 8; kk++) s += sb[(i_l * 8 + kk) * 10 + c];
        size_t o = (size_t)(blk * 4 + i_l) * 10 + c;
        float val = s * (1.0f / 256.0f);
        if (init) bij[o] = val;
        else      bij[o] += val;
    }
}

extern "C" void kernel_launch(void* const* d_in, const int* in_sizes, int n_in,
                              void* d_out, int out_size, void* d_ws, size_t ws_size,
                              hipStream_t stream) {
    const float* x      = (const float*)d_in[0];
    const float* conv_w = (const float*)d_in[1];
    const float* conv_b = (const float*)d_in[2];
    const float* prim_w = (const float*)d_in[3];
    const float* prim_b = (const float*)d_in[4];
    const float* dw     = (const float*)d_in[5];

    char* wsb = (char*)d_ws;
    unsigned short* h   = (unsigned short*)(wsb);
    unsigned short* wt  = (unsigned short*)(wsb + 52428800);
    float* pp   = (float*)(wsb + 63045632);
    float* U    = (float*)(wsb + 81920000);
    float* dwT2 = (float*)(wsb + 91357184);
    float* part = (float*)(wsb + 97255424);
    float* csm  = (float*)(wsb + 102498304);
    float* bij  = (float*)(wsb + 102544384);
    float* outT = (float*)(wsb + 102590464);
    float* UT   = (float*)(wsb + 102754304);
    unsigned short* wb1 = (unsigned short*)(wsb + 112191488);
    float* dout = (float*)d_out;

    k_makew<<<dim3(32, 8), 256, 0, stream>>>(prim_w, wt);
    k_prep2<<<161, 256, 0, stream>>>(conv_w, dw, wb1, dwT2);
    k_conv1m<<<dim3(256, 2), 256, 0, stream>>>(x, wb1, conv_b, h);
    k_conv2d<<<dim3(72, 4, 2), 256, 0, stream>>>(h, wt, pp);
    k_squash1<<<2048, 256, 0, stream>>>(pp, prim_b, U);
    k_ut<<<dim3(144, 4), 256, 0, stream>>>(U, UT);

    // iter 0 (b_ij = 0 -> uniform c; g2uv init writes bij)
    k_gemm1<<<dim3(8, 32), 256, 0, stream>>>(U, dwT2, csm, part, 1);
    k_redsq<<<256, 256, 0, stream>>>(part, outT, dout, 0);
    k_g2uv<<<288, 256, 0, stream>>>(UT, outT, dw, bij, 1);
    k_softmax<<<10, 256, 0, stream>>>(bij, csm);
    // iter 1
    k_gemm1<<<dim3(8, 32), 256, 0, stream>>>(U, dwT2, csm, part, 0);
    k_redsq<<<256, 256, 0, stream>>>(part, outT, dout, 0);
    k_g2uv<<<288, 256, 0, stream>>>(UT, outT, dw, bij, 0);
    k_softmax<<<10, 256, 0, stream>>>(bij, csm);
    // iter 2
    k_gemm1<<<dim3(8, 32), 256, 0, stream>>>(U, dwT2, csm, part, 0);
    k_redsq<<<256, 256, 0, stream>>>(part, outT, dout, 1);
}

// Round 9
// 519.988 us; speedup vs baseline: 1.9371x; 1.9371x over previous
//
#include <hip/hip_runtime.h>
#include <cstdint>
#include <cstddef>

// ---------------------------------------------------------------------------
// CapsNet forward. Round 9:
//  - conv2m: round-5 proven LDS kernel (z=2, 128ic/round, 48KB, 0-conflict).
//  - k_prep: makew + conv1-weight-frags + dwT2 merged into one launch.
//  - softmax folded INTO gemm1 (per-block recompute from bij; kills 2
//    latency-bound launches + csm buffer).
//  - 13 launches total.
// Workspace (bytes):
//   h    [0, 52428800)           bf16 [b][pix400][ic256]
//   wt   [52428800, 63045632)    bf16 [k81][oc256][ic256]
//   pp   [63045632, 81920000)    f32  2 z-halves of [b][oc][36]
//   U    [81920000, 91357184)    f32  [b][ik]
//   dwT2 [91357184, 97255424)    f32  [co160][ik9216]
//   part [97255424, 102498304)   f32  [kc32][b256][co160]
//   bij  [102544384,102590464)   f32  [i][c]
//   outT [102590464,102754304)   f32  [co160][b256]
//   UT   [102754304,112191488)   f32  [ik9216][b256]
//   wb1  [112191488,112240640)   bf16 conv1 frag-linear weights
// ---------------------------------------------------------------------------

typedef __attribute__((ext_vector_type(8))) short short8;
typedef __attribute__((ext_vector_type(4))) float f32x4;

#define PHALF 2359296

__device__ __forceinline__ unsigned short f2bf_rn(float x) {
    unsigned u = __float_as_uint(x);
    unsigned r = (u + 0x7fffu + ((u >> 16) & 1u)) >> 16;
    return (unsigned short)r;
}

// Merged prep. grid 417:
//   blk 0..255  : prim_w -> wt[k][oc][ic] bf16   (ocg=blk>>3, icg=blk&7)
//   blk 256     : conv1 weight frags wb1
//   blk 257..416: dw -> dwT2[co160][ik9216]
__global__ void k_prep(const float* __restrict__ w2, const float* __restrict__ cw,
                       const float* __restrict__ dw,
                       unsigned short* __restrict__ wt,
                       unsigned short* __restrict__ wb1,
                       float* __restrict__ dwT2) {
    __shared__ float lw[20736];
    int blk = blockIdx.x, t = threadIdx.x;
    if (blk < 256) {
        int ocg = blk >> 3, icg = blk & 7;
        for (int idx = t; idx < 20736; idx += 256) {
            int row = idx / 81, k = idx % 81;
            int oc_l = row >> 5, ic_l = row & 31;
            lw[idx] = w2[((size_t)(ocg * 8 + oc_l) * 256 + icg * 32 + ic_l) * 81 + k];
        }
        __syncthreads();
        for (int idx = t; idx < 2592; idx += 256) {
            int k = idx >> 5;
            int r = idx & 31;
            int oc_l = r >> 2, sl = r & 3;
            unsigned short hi8[8];
            #pragma unroll
            for (int j = 0; j < 8; j++)
                hi8[j] = f2bf_rn(lw[(oc_l * 32 + sl * 8 + j) * 81 + k]);
            size_t o = ((size_t)(k * 256 + ocg * 8 + oc_l)) * 256 + icg * 32 + sl * 8;
            *(uint4*)&wt[o] = *(uint4*)hi8;
        }
    } else if (blk == 256) {
        for (int idx = t; idx < 24576; idx += 256) {
            int j = idx & 7, lane = (idx >> 3) & 63;
            int q = (idx >> 9) % 3, nt = idx / 1536;
            int oc = nt * 16 + (lane & 15);
            int kg = q * 32 + (lane >> 4) * 8 + j;
            float v = (kg < 81) ? cw[oc * 81 + kg] : 0.f;
            wb1[idx] = f2bf_rn(v);
        }
    } else {
        int co = blk - 257;                   // 0..159
        int c = co >> 4, o = co & 15;
        const float* base = dw + c * 128 + o * 8;
        float* out = dwT2 + (size_t)co * 9216;
        for (int idx = t; idx < 9216; idx += 256) {
            int i = idx >> 3, k = idx & 7;
            out[idx] = base[(size_t)i * 1280 + k];
        }
    }
}

// MFMA conv1: grid (256 b, 2 ng), block 256 (4 waves). Validated round 6/8.
__global__ __launch_bounds__(256) void k_conv1m(
    const float* __restrict__ x, const unsigned short* __restrict__ wb1,
    const float* __restrict__ cb, unsigned short* __restrict__ h)
{
    __shared__ unsigned short xb[900];   // [30 rows][30 cols], zero-padded
    int b = blockIdx.x, ng = blockIdx.y, t = threadIdx.x;
    int w = t >> 6, l = t & 63;
    for (int idx = t; idx < 900; idx += 256) {
        int row = idx / 30, col = idx % 30;
        float v = (row < 28 && col < 28) ? x[(size_t)b * 784 + row * 28 + col] : 0.f;
        xb[idx] = f2bf_rn(v);
    }
    __syncthreads();
    int lane16 = l & 15, l4 = l >> 4;
    int ntile = (w == 0) ? 7 : 6;
    short8 afr[7][3];
    for (int i = 0; i < 7; i++) {
        if (i < ntile) {
            int mt = w + 4 * i;
            int pix = mt * 16 + lane16;
            int py = pix / 20, px = pix % 20;
            #pragma unroll
            for (int qq = 0; qq < 3; qq++) {
                int kbase = qq * 32 + l4 * 8;
                unsigned short tmp[8];
                int ky = kbase / 9, kx = kbase - 9 * (kbase / 9);
                #pragma unroll
                for (int j = 0; j < 8; j++) {
                    tmp[j] = xb[(py + ky) * 30 + px + kx];
                    kx++; if (kx == 9) { kx = 0; ky++; }
                }
                afr[i][qq] = *(short8*)tmp;
            }
        }
    }
    for (int nt0 = 0; nt0 < 8; nt0++) {
        int nt = ng * 8 + nt0;
        short8 bfr[3];
        #pragma unroll
        for (int qq = 0; qq < 3; qq++)
            bfr[qq] = *(const short8*)&wb1[(nt * 3 + qq) * 512 + l * 8];
        float bias = cb[nt * 16 + lane16];
        f32x4 acc[7] = {};
        for (int i = 0; i < 7; i++) {
            if (i < ntile) {
                #pragma unroll
                for (int qq = 0; qq < 3; qq++)
                    acc[i] = __builtin_amdgcn_mfma_f32_16x16x32_bf16(afr[i][qq], bfr[qq], acc[i], 0, 0, 0);
            }
        }
        for (int i = 0; i < 7; i++) {
            if (i < ntile) {
                int mt = w + 4 * i;
                int pixb = mt * 16 + l4 * 4;
                size_t base = ((size_t)b * 400 + pixb) * 256 + nt * 16 + lane16;
                #pragma unroll
                for (int r = 0; r < 4; r++) {
                    float v = fmaxf(acc[i][r] + bias, 0.f);
                    h[base + (size_t)r * 256] = f2bf_rn(v);
                }
            }
        }
    }
}

// Implicit-GEMM bf16 MFMA conv2 (round-5 proven config).
// grid (72 mb, 4 nb, 2 z), block 256. 128 pix x 64 oc; 81 rounds x 128 ic
// staged as two 64-ic halves with 64-short rows + 3-bit XOR swizzle (0-conflict).
__global__ __launch_bounds__(256) void k_conv2m(
    const unsigned short* __restrict__ h,
    const unsigned short* __restrict__ wt,
    float* __restrict__ pp)
{
    __shared__ unsigned short smem[24576];   // 49152 B
    const int t = threadIdx.x;
    const int w = t >> 6, l = t & 63;
    const int mb = blockIdx.x, nb = blockIdx.y, z = blockIdx.z;

    const unsigned short* src;
    int nld, sbase;
    unsigned rowbase[16];
    if (w < 2) {
        src = h; nld = 16; sbase = w * 8192;
        #pragma unroll
        for (int ld = 0; ld < 16; ld++) {
            int row = ld * 8 + (l >> 3);           // pixel local 0..127
            int c = l & 7;
            int g = c ^ (row & 7);
            int P = mb * 128 + row;
            int b = P / 36, o = P % 36;
            int oy = o / 6, ox = o % 6;
            rowbase[ld] = (unsigned)((b * 400 + oy * 40 + ox * 2) * 256 + z * 128 + w * 64 + g * 8);
        }
    } else {
        int hh = w - 2;
        src = wt; nld = 8; sbase = 16384 + hh * 4096;
        #pragma unroll
        for (int ld = 0; ld < 8; ld++) {
            int oc = ld * 8 + (l >> 3);            // 0..63
            int c = l & 7;
            int g = c ^ (oc & 7);
            rowbase[ld] = (unsigned)((nb * 64 + oc) * 256 + z * 128 + hh * 64 + g * 8);
        }
    }

    const int wm = w & 1, wn = w >> 1;
    const int lane16 = l & 15, q = l >> 4;

    f32x4 acc[4][2] = {};

    for (int ky = 0; ky < 9; ky++) {
        for (int kx = 0; kx < 9; kx++) {
            const unsigned kofs = (w < 2) ? (unsigned)((ky * 20 + kx) * 256)
                                          : (unsigned)((ky * 9 + kx) * 65536);
            __syncthreads();
            for (int ld = 0; ld < nld; ld++) {
                __builtin_amdgcn_global_load_lds(
                    (const __attribute__((address_space(1))) unsigned int*)(const void*)(src + rowbase[ld] + kofs),
                    (__attribute__((address_space(3))) unsigned int*)(void*)(smem + sbase + ld * 512),
                    16, 0, 0);
            }
            __syncthreads();
            #pragma unroll
            for (int hh = 0; hh < 2; hh++) {
                #pragma unroll
                for (int ic2 = 0; ic2 < 2; ic2++) {
                    short8 a[4], b[2];
                    #pragma unroll
                    for (int mt = 0; mt < 4; mt++) {
                        int pixL = wm * 64 + mt * 16 + lane16;
                        int ps = (ic2 * 4 + q) ^ (pixL & 7);
                        a[mt] = *(const short8*)(smem + hh * 8192 + pixL * 64 + ps * 8);
                    }
                    #pragma unroll
                    for (int nt = 0; nt < 2; nt++) {
                        int ocL = wn * 32 + nt * 16 + lane16;
                        int ps = (ic2 * 4 + q) ^ (ocL & 7);
                        b[nt] = *(const short8*)(smem + 16384 + hh * 4096 + ocL * 64 + ps * 8);
                    }
                    #pragma unroll
                    for (int mt = 0; mt < 4; mt++)
                        #pragma unroll
                        for (int nt = 0; nt < 2; nt++)
                            acc[mt][nt] = __builtin_amdgcn_mfma_f32_16x16x32_bf16(a[mt], b[nt], acc[mt][nt], 0, 0, 0);
                }
            }
        }
    }

    float* pout = pp + (size_t)z * PHALF;
    #pragma unroll
    for (int mt = 0; mt < 4; mt++) {
        int pixG = mb * 128 + wm * 64 + mt * 16 + q * 4;
        int b = pixG / 36, p36 = pixG % 36;
        #pragma unroll
        for (int nt = 0; nt < 2; nt++) {
            int oc = nb * 64 + wn * 32 + nt * 16 + lane16;
            f32x4 v = acc[mt][nt];
            *(f32x4*)&pout[((size_t)(b * 256 + oc)) * 36 + p36] = v;
        }
    }
}

__global__ void k_squash1(const float* __restrict__ pp, const float* __restrict__ prim_b,
                          float* __restrict__ U) {
    __shared__ float red[4];
    int b = blockIdx.x >> 3, cap = blockIdx.x & 7;
    int t = threadIdx.x;
    const float* pa = pp + ((size_t)b * 256 + cap * 32) * 36;
    const float* pc = pa + PHALF;
    float v[5];
    float ss = 0.f;
    #pragma unroll
    for (int j = 0; j < 5; j++) {
        int idx = t + j * 256;
        if (idx < 1152) {
            int ch_l = idx / 36;
            float val = pa[idx] + pc[idx] + prim_b[cap * 32 + ch_l];
            v[j] = val; ss += val * val;
        } else v[j] = 0.f;
    }
    for (int off = 32; off; off >>= 1) ss += __shfl_down(ss, off);
    if ((t & 63) == 0) red[t >> 6] = ss;
    __syncthreads();
    float n2 = red[0] + red[1] + red[2] + red[3];
    float f = (n2 / (1.0f + n2)) / (sqrtf(n2) + 1e-10f);
    #pragma unroll
    for (int j = 0; j < 5; j++) {
        int idx = t + j * 256;
        if (idx < 1152) U[(size_t)b * 9216 + idx * 8 + cap] = v[j] * f;
    }
}

// U[b][ik] -> UT[ik][b], 64x64 tiles (coalesced both sides)
__global__ void k_ut(const float* __restrict__ U, float* __restrict__ UT) {
    __shared__ float tl[64][65];
    int ikb = blockIdx.x, bb = blockIdx.y, t = threadIdx.x;
    for (int idx = t; idx < 1024; idx += 256) {
        int row = idx >> 4, c4 = idx & 15;
        float4 v = *(const float4*)&U[(size_t)(bb * 64 + row) * 9216 + ikb * 64 + c4 * 4];
        tl[c4 * 4 + 0][row] = v.x;
        tl[c4 * 4 + 1][row] = v.y;
        tl[c4 * 4 + 2][row] = v.z;
        tl[c4 * 4 + 3][row] = v.w;
    }
    __syncthreads();
    for (int idx = t; idx < 1024; idx += 256) {
        int row = idx >> 4, c4 = idx & 15;
        float4 v = make_float4(tl[row][c4 * 4 + 0], tl[row][c4 * 4 + 1],
                               tl[row][c4 * 4 + 2], tl[row][c4 * 4 + 3]);
        *(float4*)&UT[(size_t)(ikb * 64 + row) * 256 + bb * 64 + c4 * 4] = v;
    }
}

// s_j partial GEMM with INLINE softmax (from bij) + c_ij folded into staging.
// grid (8 mb, 32 kc), block 256.
__global__ __launch_bounds__(256) void k_gemm1(const float* __restrict__ U,
                                               const float* __restrict__ dwT2,
                                               const float* __restrict__ bij,
                                               float* __restrict__ part,
                                               int uniform) {
    __shared__ float Us[32 * 36];
    __shared__ float WsT[5120];
    __shared__ float cl[360];
    __shared__ float red[256];
    __shared__ float cmx[10], cinv[10];
    int mb = blockIdx.x, kc = blockIdx.y, t = threadIdx.x;
    int tc = t & 15, tb = t >> 4;

    if (!uniform) {
        // per-class max over i (all 1152), then sum of exp
        int c = t % 10, g = t / 10;          // 250 active threads, 25 groups
        float lmx = -1e30f;
        if (t < 250)
            for (int i = g; i < 1152; i += 25) lmx = fmaxf(lmx, bij[i * 10 + c]);
        red[t] = lmx;
        __syncthreads();
        if (t < 10) {
            float m = -1e30f;
            #pragma unroll
            for (int g2 = 0; g2 < 25; g2++) m = fmaxf(m, red[g2 * 10 + t]);
            cmx[t] = m;
        }
        __syncthreads();
        float lsum = 0.f;
        if (t < 250) {
            float m = cmx[c];
            for (int i = g; i < 1152; i += 25) lsum += expf(bij[i * 10 + c] - m);
        }
        red[t] = lsum;
        __syncthreads();
        if (t < 10) {
            float s2 = 0.f;
            #pragma unroll
            for (int g2 = 0; g2 < 25; g2++) s2 += red[g2 * 10 + t];
            cinv[t] = 1.0f / s2;
        }
        __syncthreads();
        for (int idx = t; idx < 360; idx += 256) {
            int i = kc * 36 + idx / 10, c2 = idx % 10;
            cl[idx] = expf(bij[i * 10 + c2] - cmx[c2]) * cinv[c2];
        }
    }

    const float uscale = 1.0f / 1152.0f;
    float acc[2][10] = {};
    for (int ks = 0; ks < 9; ks++) {
        __syncthreads();
        {
            int bb = t >> 3, k4 = t & 7;
            *(float4*)&Us[bb * 36 + k4 * 4] =
                *(const float4*)&U[(size_t)(mb * 32 + bb) * 9216 + kc * 288 + ks * 32 + k4 * 4];
        }
        #pragma unroll
        for (int pass = 0; pass < 5; pass++) {
            int s = t + pass * 256;
            int co = s >> 3, p = s & 7;
            int kq = p ^ (co & 7);
            int ikl = ks * 32 + kq * 4;
            float4 v = *(const float4*)&dwT2[(size_t)co * 9216 + kc * 288 + ikl];
            float sc = uniform ? uscale : cl[(ikl >> 3) * 10 + (co >> 4)];
            v.x *= sc; v.y *= sc; v.z *= sc; v.w *= sc;
            *(float4*)&WsT[s * 4] = v;
        }
        __syncthreads();
        float a0[32], a1[32];
        #pragma unroll
        for (int kq = 0; kq < 8; kq++) {
            float4 v0 = *(const float4*)&Us[(tb * 2) * 36 + kq * 4];
            float4 v1 = *(const float4*)&Us[(tb * 2 + 1) * 36 + kq * 4];
            a0[kq * 4 + 0] = v0.x; a0[kq * 4 + 1] = v0.y; a0[kq * 4 + 2] = v0.z; a0[kq * 4 + 3] = v0.w;
            a1[kq * 4 + 0] = v1.x; a1[kq * 4 + 1] = v1.y; a1[kq * 4 + 2] = v1.z; a1[kq * 4 + 3] = v1.w;
        }
        #pragma unroll
        for (int j = 0; j < 10; j++) {
            int co = tc + 16 * j;
            int cx = co & 7, cbase = co * 32;
            #pragma unroll
            for (int kq = 0; kq < 8; kq++) {
                float4 wv = *(const float4*)&WsT[cbase + ((kq ^ cx) << 2)];
                acc[0][j] += a0[kq * 4 + 0] * wv.x; acc[0][j] += a0[kq * 4 + 1] * wv.y;
                acc[0][j] += a0[kq * 4 + 2] * wv.z; acc[0][j] += a0[kq * 4 + 3] * wv.w;
                acc[1][j] += a1[kq * 4 + 0] * wv.x; acc[1][j] += a1[kq * 4 + 1] * wv.y;
                acc[1][j] += a1[kq * 4 + 2] * wv.z; acc[1][j] += a1[kq * 4 + 3] * wv.w;
            }
        }
    }
    #pragma unroll
    for (int r = 0; r < 2; r++)
        #pragma unroll
        for (int j = 0; j < 10; j++)
            part[(size_t)kc * 40960 + (mb * 32 + tb * 2 + r) * 160 + tc + 16 * j] = acc[r][j];
}

// reduce 32 partials + class-axis squash; iters 0/1 -> outT, iter 2 -> dout
__global__ void k_redsq(const float* __restrict__ part, float* __restrict__ outT,
                        float* __restrict__ dout, int last) {
    __shared__ float sl[160];
    __shared__ float n2s[16];
    int b = blockIdx.x, t = threadIdx.x;
    float s = 0.f;
    if (t < 160) {
        for (int kc = 0; kc < 32; kc++) s += part[(size_t)kc * 40960 + b * 160 + t];
        sl[t] = s;
    }
    __syncthreads();
    if (t < 16) {
        float n2 = 0.f;
        #pragma unroll
        for (int c = 0; c < 10; c++) { float v = sl[c * 16 + t]; n2 += v * v; }
        n2s[t] = n2;
    }
    __syncthreads();
    if (t < 160) {
        float n2 = n2s[t & 15];
        float f = (n2 / (1.0f + n2)) / (sqrtf(n2) + 1e-10f);
        float r = s * f;
        if (last) dout[(size_t)b * 160 + t] = r;
        else      outT[(size_t)t * 256 + b] = r;
    }
}

// Fused agreement via UT/outT. grid 288 (4 i's each), block 256.
__global__ __launch_bounds__(256) void k_g2uv(const float* __restrict__ UT,
                                              const float* __restrict__ outTg,
                                              const float* __restrict__ dw,
                                              float* __restrict__ bij, int init) {
    __shared__ float UsT[1024];
    __shared__ float OsT[5120];
    __shared__ float dwl[5120];
    __shared__ float sb[320];
    int blk = blockIdx.x, t = threadIdx.x;
    int tc = t & 15, tm = t >> 4;
    for (int idx = t; idx < 5120; idx += 256)
        dwl[idx] = dw[(size_t)blk * 5120 + idx];
    float acc[2][10] = {};
    for (int bs = 0; bs < 256; bs += 32) {
        __syncthreads();
        {
            int m = t >> 3, p = t & 7;
            int kq = p ^ (m & 7);
            *(float4*)&UsT[t * 4] =
                *(const float4*)&UT[(size_t)(blk * 32 + m) * 256 + bs + kq * 4];
        }
        #pragma unroll
        for (int pass = 0; pass < 5; pass++) {
            int s = t + pass * 256;
            int co = s >> 3, p = s & 7;
            int kq = p ^ (co & 7);
            *(float4*)&OsT[s * 4] =
                *(const float4*)&outTg[(size_t)co * 256 + bs + kq * 4];
        }
        __syncthreads();
        float a0[32], a1[32];
        int m0 = tm * 2, m1 = tm * 2 + 1;
        #pragma unroll
        for (int kq = 0; kq < 8; kq++) {
            float4 v0 = *(const float4*)&UsT[m0 * 32 + ((kq ^ (m0 & 7)) << 2)];
            float4 v1 = *(const float4*)&UsT[m1 * 32 + ((kq ^ (m1 & 7)) << 2)];
            a0[kq * 4 + 0] = v0.x; a0[kq * 4 + 1] = v0.y; a0[kq * 4 + 2] = v0.z; a0[kq * 4 + 3] = v0.w;
            a1[kq * 4 + 0] = v1.x; a1[kq * 4 + 1] = v1.y; a1[kq * 4 + 2] = v1.z; a1[kq * 4 + 3] = v1.w;
        }
        #pragma unroll
        for (int j = 0; j < 10; j++) {
            int co = tc + 16 * j;
            int cx = co & 7, cbase = co * 32;
            #pragma unroll
            for (int kq = 0; kq < 8; kq++) {
                float4 wv = *(const float4*)&OsT[cbase + ((kq ^ cx) << 2)];
                acc[0][j] += a0[kq * 4 + 0] * wv.x; acc[0][j] += a0[kq * 4 + 1] * wv.y;
                acc[0][j] += a0[kq * 4 + 2] * wv.z; acc[0][j] += a0[kq * 4 + 3] * wv.w;
                acc[1][j] += a1[kq * 4 + 0] * wv.x; acc[1][j] += a1[kq * 4 + 1] * wv.y;
                acc[1][j] += a1[kq * 4 + 2] * wv.z; acc[1][j] += a1[kq * 4 + 3] * wv.w;
            }
        }
    }
    #pragma unroll
    for (int r = 0; r < 2; r++) {
        int ik_l = tm * 2 + r;
        int i_l = ik_l >> 3, k = ik_l & 7;
        #pragma unroll
        for (int j = 0; j < 10; j++) {
            float v = acc[r][j] * dwl[i_l * 1280 + (j * 16 + tc) * 8 + k];
            v += __shfl_down(v, 8, 16);
            v += __shfl_down(v, 4, 16);
            v += __shfl_down(v, 2, 16);
            v += __shfl_down(v, 1, 16);
            if (tc == 0) sb[ik_l * 10 + j] = v;
        }
    }
    __syncthreads();
    if (t < 40) {
        int i_l = t / 10, c = t % 10;
        float s = 0.f;
        #pragma unroll
        for (int kk = 0; kk < 8; kk++) s += sb[(i_l * 8 + kk) * 10 + c];
        size_t o = (size_t)(blk * 4 + i_l) * 10 + c;
        float val = s * (1.0f / 256.0f);
        if (init) bij[o] = val;
        else      bij[o] += val;
    }
}

extern "C" void kernel_launch(void* const* d_in, const int* in_sizes, int n_in,
                              void* d_out, int out_size, void* d_ws, size_t ws_size,
                              hipStream_t stream) {
    const float* x      = (const float*)d_in[0];
    const float* conv_w = (const float*)d_in[1];
    const float* conv_b = (const float*)d_in[2];
    const float* prim_w = (const float*)d_in[3];
    const float* prim_b = (const float*)d_in[4];
    const float* dw     = (const float*)d_in[5];

    char* wsb = (char*)d_ws;
    unsigned short* h   = (unsigned short*)(wsb);
    unsigned short* wt  = (unsigned short*)(wsb + 52428800);
    float* pp   = (float*)(wsb + 63045632);
    float* U    = (float*)(wsb + 81920000);
    float* dwT2 = (float*)(wsb + 91357184);
    float* part = (float*)(wsb + 97255424);
    float* bij  = (float*)(wsb + 102544384);
    float* outT = (float*)(wsb + 102590464);
    float* UT   = (float*)(wsb + 102754304);
    unsigned short* wb1 = (unsigned short*)(wsb + 112191488);
    float* dout = (float*)d_out;

    k_prep<<<417, 256, 0, stream>>>(prim_w, conv_w, dw, wt, wb1, dwT2);
    k_conv1m<<<dim3(256, 2), 256, 0, stream>>>(x, wb1, conv_b, h);
    k_conv2m<<<dim3(72, 4, 2), 256, 0, stream>>>(h, wt, pp);
    k_squash1<<<2048, 256, 0, stream>>>(pp, prim_b, U);
    k_ut<<<dim3(144, 4), 256, 0, stream>>>(U, UT);

    // iter 0 (b_ij = 0 -> uniform c; g2uv init writes bij)
    k_gemm1<<<dim3(8, 32), 256, 0, stream>>>(U, dwT2, bij, part, 1);
    k_redsq<<<256, 256, 0, stream>>>(part, outT, dout, 0);
    k_g2uv<<<288, 256, 0, stream>>>(UT, outT, dw, bij, 1);
    // iter 1
    k_gemm1<<<dim3(8, 32), 256, 0, stream>>>(U, dwT2, bij, part, 0);
    k_redsq<<<256, 256, 0, stream>>>(part, outT, dout, 0);
    k_g2uv<<<288, 256, 0, stream>>>(UT, outT, dw, bij, 0);
    // iter 2
    k_gemm1<<<dim3(8, 32), 256, 0, stream>>>(U, dwT2, bij, part, 0);
    k_redsq<<<256, 256, 0, stream>>>(part, outT, dout, 1);
}